// Round 13
// baseline (4557.325 us; speedup 1.0000x reference)
//
#include <hip/hip_runtime.h>
#include <hip/hip_bf16.h>

// VanillaRNN: B=512, S=256, V=128, E=128, H=512  (float32 in/out)
// 256 blocks, cooperative launch, static LDS. Per XCD (HW_REG_XCC_ID): 2 batch-groups
// (32 rows) x {8 stage0 blocks, 8 stage1 blocks} (64-col slices). Weights in LDS.
// CONSUMER FIX (R12 post-mortem): vector-L1 invalidate must be `buffer_inv sc1`
// (agent-scope acquire, what LLVM emits) — `sc0` was a no-op, so plain h-loads hit
// STALE L1 lines self-cached 4 steps earlier. R6 only passed because its 128KB/step
// weight stream capacity-flushed L1; LDS weights (R7+) removed that accidental flush.
// Producer (R11 hardening kept): LDS-stage C-tile -> 8B relaxed agent atomic stores
// (L2-direct) -> vmcnt(0) -> barrier -> flag. Projection in stage0, lag 4.

#define Bb 512
#define Ss 256
#define Vv 128
#define Ee 128
#define Hh 512

typedef _Float16 f16;
typedef __attribute__((ext_vector_type(8))) _Float16 f16x8;
typedef __attribute__((ext_vector_type(4))) float f32x4;

// ws layout
#define OFF_H0   0u            // [4][512][512] f16
#define OFF_H1   2097152u      // [4][512][512] f16
#define OFF_W0T  4194304u      // [512][640]  f16 (W0T[c][k], k<128:Wih0, else Whh0)
#define OFF_W1T  4849664u      // [512][1024] f16 (W1T[c][k], k<512:Wih1, else Whh1)
#define OFF_WOT  5898240u      // [128][512]  f16 (WoutT[v][k])
#define OFF_EMB  6029312u      // [128][128]  f16
#define OFF_FLAG 6062080u      // [16 groups][16] int
#define OFF_CTR  6063104u      // [16] int per-XCD slot counters
#define WS_TOTAL 6063168u

// static LDS layout — row-major, +16B pad per row (strides are 16B multiples)
// stage0: lw0 [64] stride 1296 @0 | lwo [16] stride 1040 @82944 | lemb [128] stride 272 @99584
// stage1: lw1 [64] stride 2064 @0
// both:   hstg [32][64] f16 @134400 (4KB h-output staging tile)
#define L_WO   82944
#define L_EMB  99584
#define ST_W0  1296
#define ST_WO  1040
#define ST_EM  272
#define ST_W1  2064
#define L_HS   134400
#define LDS_BYTES 138496

__device__ __forceinline__ f16x8 ld8(const f16* p) {
    return *reinterpret_cast<const f16x8*>(p);
}
__device__ __forceinline__ f16x8 lds_frag(const char* lds, int rowByte, int kElem) {
    return *reinterpret_cast<const f16x8*>(lds + rowByte + kElem * 2);
}
// Agent-acquire style vL1 invalidate: drain vmem, then buffer_inv sc1 (LLVM's gfx940+
// agent-acquire sequence). Subsequent plain loads force-miss L1 and hit the XCD L2.
#define INV_L1() asm volatile("s_waitcnt vmcnt(0)\n\tbuffer_inv sc1" ::: "memory")
#define MFMA16(a, b, c) __builtin_amdgcn_mfma_f32_16x16x32_f16((a), (b), (c), 0, 0, 0)

__global__ void prep_kernel(const float* __restrict__ Wih0, const float* __restrict__ Whh0,
                            const float* __restrict__ Wih1, const float* __restrict__ Whh1,
                            const float* __restrict__ Wout, const float* __restrict__ emb,
                            char* __restrict__ ws)
{
    f16* w0t = (f16*)(ws + OFF_W0T);
    f16* w1t = (f16*)(ws + OFF_W1T);
    f16* wot = (f16*)(ws + OFF_WOT);
    f16* e16 = (f16*)(ws + OFF_EMB);
    const int N0 = 512 * 640, N1 = 512 * 1024, N2 = 128 * 512, NE = 128 * 128;
    int i = blockIdx.x * blockDim.x + threadIdx.x;
    if (i < N0) {
        int c = i / 640, k = i - c * 640;
        w0t[i] = (f16)((k < 128) ? Wih0[k * 512 + c] : Whh0[(k - 128) * 512 + c]);
    } else if (i < N0 + N1) {
        int j = i - N0;
        int c = j >> 10, k = j & 1023;
        w1t[j] = (f16)((k < 512) ? Wih1[k * 512 + c] : Whh1[(k - 512) * 512 + c]);
    } else if (i < N0 + N1 + N2) {
        int j = i - (N0 + N1);
        int v = j >> 9, k = j & 511;
        wot[j] = (f16)(Wout[k * 128 + v]);
    } else if (i < N0 + N1 + N2 + NE) {
        int j = i - (N0 + N1 + N2);
        e16[j] = (f16)(emb[j]);
    }
}

__global__ __launch_bounds__(512)
void rnn_kernel(
    const int* __restrict__ x,
    const float* __restrict__ bih0, const float* __restrict__ bhh0,
    const float* __restrict__ bih1, const float* __restrict__ bhh1,
    const float* __restrict__ bout, float* __restrict__ out,
    f16* __restrict__ h0buf, f16* __restrict__ h1buf,
    const f16* __restrict__ w0t, const f16* __restrict__ w1t,
    const f16* __restrict__ wot, const f16* __restrict__ e16,
    int* __restrict__ flags, int* __restrict__ xcdctr)
{
    static __shared__ __attribute__((aligned(16))) char lds[LDS_BYTES];
    const int tid = threadIdx.x;

    // --- dynamic XCD-local group assignment (group's 16 blocks share one L2) ---
    __shared__ __attribute__((aligned(16))) int sslot[4];
    if (tid == 0) {
        unsigned int xcc;
        asm volatile("s_getreg_b32 %0, hwreg(20, 0, 4)" : "=s"(xcc));   // HW_REG_XCC_ID
        int s = atomicAdd(&xcdctr[xcc & 15], 1);
        sslot[0] = (int)(xcc & 15);
        sslot[1] = s;
    }
    __syncthreads();
    const int xcd = sslot[0], slot = sslot[1];
    const int grp = xcd * 2 + (slot >> 4);   // batch group 0..15 (32 rows each)
    const int sub = slot & 15;
    const int stg = sub >> 3;                // 0 = layer0 (+projection), 1 = layer1
    const int jc  = sub & 7;                 // column slice 0..7 (64 cols)
    if (grp >= 16) return;
    const int row0 = grp * 32;
    const int col0 = jc * 64;

    int* gflags = flags + grp * 16;          // [0..7]=stage0, [8..15]=stage1

    __shared__ __attribute__((aligned(16))) int tok[32];
    __shared__ __attribute__((aligned(16))) float bs[64];

    const int lane = tid & 63;
    const int wv = tid >> 6;                 // wave 0..7
    const int mt = wv >> 2, nt = wv & 3;     // 2 M-tiles x 4 N-tiles
    const int ar = lane & 15;
    const int kg8 = (lane >> 4) << 3;
    const int arow = row0 + mt * 16 + ar;
    const int cB   = nt * 16 + ar;           // local output col 0..63
    const int rloc = mt * 16 + ((lane >> 4) << 2);   // local row base for C-frags

    // ---- stage weights into LDS (row-major, padded), once ----
    if (stg == 0) {
        for (int i = tid; i < 5120; i += 512) {            // lw0: 64 rows x 80 chunks
            int c = i / 80, kc = i - c * 80;
            *(f16x8*)(lds + c * ST_W0 + kc * 16) = ld8(w0t + (col0 + c) * 640 + kc * 8);
        }
        for (int i = tid; i < 1024; i += 512) {            // lwo: 16 rows x 64 chunks
            int r = i >> 6, kc = i & 63;
            *(f16x8*)(lds + L_WO + r * ST_WO + kc * 16) = ld8(wot + (jc * 16 + r) * 512 + kc * 8);
        }
        for (int i = tid; i < 2048; i += 512) {            // lemb: 128 rows x 16 chunks
            int r = i >> 4, kc = i & 15;
            *(f16x8*)(lds + L_EMB + r * ST_EM + kc * 16) = ld8(e16 + r * 128 + kc * 8);
        }
    } else {
        for (int i = tid; i < 8192; i += 512) {            // lw1: 64 rows x 128 chunks
            int c = i >> 7, kc = i & 127;
            *(f16x8*)(lds + c * ST_W1 + kc * 16) = ld8(w1t + (col0 + c) * 1024 + kc * 8);
        }
    }
    if (tid < 64) {
        bs[tid] = (stg == 0) ? (bih0[col0 + tid] + bhh0[col0 + tid])
                             : (bih1[col0 + tid] + bhh1[col0 + tid]);
    }
    __syncthreads();
    const float cbias = bs[cB];
    f16* hstg = (f16*)(lds + L_HS);

    if (stg == 0) {
        // ---- layer 0: h0(t) = tanh([emb(x_t) | h0(t-1)] @ W0 + b0) + projection of h1(t-4) ----
        const int w0Row = cB * ST_W0;
        const int vcol = jc * 16 + ar;
        const float pbias = bout[vcol];
        const int woRow = L_WO + ar * ST_WO;
        const int prow_base = row0 + mt * 16;

        for (int t = 0; t < Ss; ++t) {
            if (tid >= 64 && tid < 96) tok[tid - 64] = x[(row0 + tid - 64) * Ss + t];
            if (tid < 16) {
                const int tgt = (tid < 8) ? t : (t - 3);
                int it = 0;
                while (__hip_atomic_load(&gflags[tid], __ATOMIC_RELAXED, __HIP_MEMORY_SCOPE_AGENT) < tgt) {
                    if (++it > (1 << 18)) break;
                    __builtin_amdgcn_s_sleep(1);
                }
            }
            __syncthreads();
            INV_L1();
            const int myTok = tok[mt * 16 + ar];
            const int embRow = L_EMB + myTok * ST_EM;
            f16x8 hf[16];
            const f16* ha = h0buf + ((t + 3) & 3) * (Bb * Hh) + arow * Hh + kg8;
            #pragma unroll
            for (int kc = 0; kc < 16; ++kc) hf[kc] = ld8(ha + kc * 32);
            f32x4 a0 = {0.f,0.f,0.f,0.f}, a1 = a0, a2 = a0, a3 = a0;
            #pragma unroll
            for (int kc = 0; kc < 4; ++kc) {
                f16x8 af = lds_frag(lds, embRow, kc * 32 + kg8);
                f16x8 bw = lds_frag(lds, w0Row, kc * 32 + kg8);
                if ((kc & 3) == 0) a0 = MFMA16(af, bw, a0);
                else if ((kc & 3) == 1) a1 = MFMA16(af, bw, a1);
                else if ((kc & 3) == 2) a2 = MFMA16(af, bw, a2);
                else a3 = MFMA16(af, bw, a3);
            }
            #pragma unroll
            for (int kc = 0; kc < 16; ++kc) {
                f16x8 bw = lds_frag(lds, w0Row, 128 + kc * 32 + kg8);
                if ((kc & 3) == 0) a0 = MFMA16(hf[kc], bw, a0);
                else if ((kc & 3) == 1) a1 = MFMA16(hf[kc], bw, a1);
                else if ((kc & 3) == 2) a2 = MFMA16(hf[kc], bw, a2);
                else a3 = MFMA16(hf[kc], bw, a3);
            }
            f32x4 acc = (a0 + a1) + (a2 + a3);
            #pragma unroll
            for (int i = 0; i < 4; ++i) hstg[(rloc + i) * 64 + cB] = (f16)(tanhf(acc[i] + cbias));
            // projection of h1(t-4) -> logits(t-4); rotates across wave pairs (wv&3 == t&3)
            if (t >= 4 && (wv & 3) == (t & 3)) {
                const int tp = t - 4;
                f16x8 pf[16];
                const f16* pa = h1buf + (tp & 3) * (Bb * Hh) + (prow_base + ar) * Hh + kg8;
                #pragma unroll
                for (int kc = 0; kc < 16; ++kc) pf[kc] = ld8(pa + kc * 32);
                f32x4 p0 = {0.f,0.f,0.f,0.f}, p1 = p0, p2 = p0, p3 = p0;
                #pragma unroll
                for (int kc = 0; kc < 16; kc += 4) {
                    p0 = MFMA16(pf[kc + 0], lds_frag(lds, woRow, (kc + 0) * 32 + kg8), p0);
                    p1 = MFMA16(pf[kc + 1], lds_frag(lds, woRow, (kc + 1) * 32 + kg8), p1);
                    p2 = MFMA16(pf[kc + 2], lds_frag(lds, woRow, (kc + 2) * 32 + kg8), p2);
                    p3 = MFMA16(pf[kc + 3], lds_frag(lds, woRow, (kc + 3) * 32 + kg8), p3);
                }
                f32x4 pr = (p0 + p1) + (p2 + p3);
                float* op = out + (size_t)(prow_base + ((lane >> 4) << 2)) * (Ss * Vv) + tp * Vv + vcol;
                #pragma unroll
                for (int i = 0; i < 4; ++i) op[i * (Ss * Vv)] = pr[i] + pbias;
            }
            __syncthreads();   // hstg complete
            {   // one contiguous 8B chunk per thread -> atomic (L2-direct) store
                unsigned long long v = ((const unsigned long long*)hstg)[tid];
                unsigned long long* hg = (unsigned long long*)(h0buf + (t & 3) * (Bb * Hh)
                                            + (row0 + (tid >> 4)) * Hh + col0 + ((tid & 15) << 2));
                __hip_atomic_store(hg, v, __ATOMIC_RELAXED, __HIP_MEMORY_SCOPE_AGENT);
            }
            asm volatile("s_waitcnt vmcnt(0)" ::: "memory");   // h in L2 before flag
            __syncthreads();
            if (tid == 0)
                __hip_atomic_store(&gflags[jc], t + 1, __ATOMIC_RELAXED, __HIP_MEMORY_SCOPE_AGENT);
        }
        // ---- tail: project h1(252..255); one step per wave (wv&3), both M-tiles ----
        if (tid < 8) {
            int it = 0;
            while (__hip_atomic_load(&gflags[8 + tid], __ATOMIC_RELAXED, __HIP_MEMORY_SCOPE_AGENT) < Ss) {
                if (++it > (1 << 18)) break;
                __builtin_amdgcn_s_sleep(1);
            }
        }
        __syncthreads();
        INV_L1();
        {
            const int tp = 252 + (wv & 3);
            f16x8 pf[16];
            const f16* pa = h1buf + (tp & 3) * (Bb * Hh) + (prow_base + ar) * Hh + kg8;
            #pragma unroll
            for (int kc = 0; kc < 16; ++kc) pf[kc] = ld8(pa + kc * 32);
            f32x4 p0 = {0.f,0.f,0.f,0.f}, p1 = p0, p2 = p0, p3 = p0;
            #pragma unroll
            for (int kc = 0; kc < 16; kc += 4) {
                p0 = MFMA16(pf[kc + 0], lds_frag(lds, woRow, (kc + 0) * 32 + kg8), p0);
                p1 = MFMA16(pf[kc + 1], lds_frag(lds, woRow, (kc + 1) * 32 + kg8), p1);
                p2 = MFMA16(pf[kc + 2], lds_frag(lds, woRow, (kc + 2) * 32 + kg8), p2);
                p3 = MFMA16(pf[kc + 3], lds_frag(lds, woRow, (kc + 3) * 32 + kg8), p3);
            }
            f32x4 pr = (p0 + p1) + (p2 + p3);
            float* op = out + (size_t)(prow_base + ((lane >> 4) << 2)) * (Ss * Vv) + tp * Vv + vcol;
            #pragma unroll
            for (int i = 0; i < 4; ++i) op[i * (Ss * Vv)] = pr[i] + pbias;
        }
    } else {
        // ---- layer 1: h1(t) = tanh([h0(t) | h1(t-1)] @ W1 + b1) ----
        const int w1Row = cB * ST_W1;
        for (int t = 0; t < Ss; ++t) {
            if (tid < 16) {
                const int tgt = (tid < 8) ? (t + 1) : t;
                int it = 0;
                while (__hip_atomic_load(&gflags[tid], __ATOMIC_RELAXED, __HIP_MEMORY_SCOPE_AGENT) < tgt) {
                    if (++it > (1 << 18)) break;
                    __builtin_amdgcn_s_sleep(1);
                }
            }
            __syncthreads();
            INV_L1();
            f16x8 hf[16], gf[16];
            const f16* h0a = h0buf + (t & 3) * (Bb * Hh) + arow * Hh + kg8;
            const f16* h1a = h1buf + ((t + 3) & 3) * (Bb * Hh) + arow * Hh + kg8;
            #pragma unroll
            for (int kc = 0; kc < 16; ++kc) hf[kc] = ld8(h0a + kc * 32);
            #pragma unroll
            for (int kc = 0; kc < 16; ++kc) gf[kc] = ld8(h1a + kc * 32);
            f32x4 a0 = {0.f,0.f,0.f,0.f}, a1 = a0, a2 = a0, a3 = a0;
            #pragma unroll
            for (int kc = 0; kc < 16; kc += 4) {
                a0 = MFMA16(hf[kc + 0], lds_frag(lds, w1Row, (kc + 0) * 32 + kg8), a0);
                a1 = MFMA16(hf[kc + 1], lds_frag(lds, w1Row, (kc + 1) * 32 + kg8), a1);
                a2 = MFMA16(hf[kc + 2], lds_frag(lds, w1Row, (kc + 2) * 32 + kg8), a2);
                a3 = MFMA16(hf[kc + 3], lds_frag(lds, w1Row, (kc + 3) * 32 + kg8), a3);
            }
            #pragma unroll
            for (int kc = 0; kc < 16; kc += 4) {
                a0 = MFMA16(gf[kc + 0], lds_frag(lds, w1Row, 512 + (kc + 0) * 32 + kg8), a0);
                a1 = MFMA16(gf[kc + 1], lds_frag(lds, w1Row, 512 + (kc + 1) * 32 + kg8), a1);
                a2 = MFMA16(gf[kc + 2], lds_frag(lds, w1Row, 512 + (kc + 2) * 32 + kg8), a2);
                a3 = MFMA16(gf[kc + 3], lds_frag(lds, w1Row, 512 + (kc + 3) * 32 + kg8), a3);
            }
            f32x4 acc = (a0 + a1) + (a2 + a3);
            #pragma unroll
            for (int i = 0; i < 4; ++i) hstg[(rloc + i) * 64 + cB] = (f16)(tanhf(acc[i] + cbias));
            __syncthreads();   // hstg complete
            {
                unsigned long long v = ((const unsigned long long*)hstg)[tid];
                unsigned long long* hg = (unsigned long long*)(h1buf + (t & 3) * (Bb * Hh)
                                            + (row0 + (tid >> 4)) * Hh + col0 + ((tid & 15) << 2));
                __hip_atomic_store(hg, v, __ATOMIC_RELAXED, __HIP_MEMORY_SCOPE_AGENT);
            }
            asm volatile("s_waitcnt vmcnt(0)" ::: "memory");
            __syncthreads();
            if (tid == 0)
                __hip_atomic_store(&gflags[8 + jc], t + 1, __ATOMIC_RELAXED, __HIP_MEMORY_SCOPE_AGENT);
        }
    }
}

extern "C" void kernel_launch(void* const* d_in, const int* in_sizes, int n_in,
                              void* d_out, int out_size, void* d_ws, size_t ws_size,
                              hipStream_t stream) {
    const int*   x    = (const int*)d_in[0];
    const float* emb  = (const float*)d_in[1];
    const float* Wih0 = (const float*)d_in[2];
    const float* bih0 = (const float*)d_in[3];
    const float* Whh0 = (const float*)d_in[4];
    const float* bhh0 = (const float*)d_in[5];
    const float* Wih1 = (const float*)d_in[6];
    const float* bih1 = (const float*)d_in[7];
    const float* Whh1 = (const float*)d_in[8];
    const float* bhh1 = (const float*)d_in[9];
    const float* Wout = (const float*)d_in[10];
    const float* bout = (const float*)d_in[11];
    float* out = (float*)d_out;
    char*  ws  = (char*)d_ws;

    hipMemsetAsync(d_ws, 0, WS_TOTAL, stream);

    {
        const int total = 512 * 640 + 512 * 1024 + 128 * 512 + 128 * 128;
        prep_kernel<<<(total + 1023) / 1024, 1024, 0, stream>>>(Wih0, Whh0, Wih1, Whh1, Wout, emb, ws);
    }

    f16* h0buf = (f16*)(ws + OFF_H0);
    f16* h1buf = (f16*)(ws + OFF_H1);
    f16* w0t   = (f16*)(ws + OFF_W0T);
    f16* w1t   = (f16*)(ws + OFF_W1T);
    f16* wot   = (f16*)(ws + OFF_WOT);
    f16* e16   = (f16*)(ws + OFF_EMB);
    int* flags = (int*)(ws + OFF_FLAG);
    int* ctr   = (int*)(ws + OFF_CTR);

    void* args[] = { (void*)&x, (void*)&bih0, (void*)&bhh0, (void*)&bih1, (void*)&bhh1,
                     (void*)&bout, (void*)&out, (void*)&h0buf, (void*)&h1buf,
                     (void*)&w0t, (void*)&w1t, (void*)&wot, (void*)&e16,
                     (void*)&flags, (void*)&ctr };
    hipLaunchCooperativeKernel((void*)rnn_kernel, dim3(256), dim3(512), args, 0, stream);
}

// Round 14
// 4498.520 us; speedup vs baseline: 1.0131x; 1.0131x over previous
//
#include <hip/hip_runtime.h>
#include <hip/hip_bf16.h>

// VanillaRNN: B=512, S=256, V=128, E=128, H=512  (float32 in/out)
// 256 blocks, cooperative launch, static LDS. Per XCD (HW_REG_XCC_ID): 2 batch-groups
// (32 rows) x {8 stage0 blocks, 8 stage1 blocks} (64-col slices). Weights in LDS.
// Consumer (R13-proven): s_waitcnt vmcnt(0) + buffer_inv sc1 (agent-acquire) per step,
// then plain vector loads — h served from the XCD-shared L2.
// Producer (R14: back to R6-style): plain write-through stores into L2, __syncthreads
// (drains vmcnt) then relaxed agent-atomic flag. R13's atomic-store producer pushed h
// to IF/HBM (FETCH 141MB, WRITE 330MB, 17.8us/step) — plain stores keep h L2-local.

#define Bb 512
#define Ss 256
#define Vv 128
#define Ee 128
#define Hh 512

typedef _Float16 f16;
typedef __attribute__((ext_vector_type(8))) _Float16 f16x8;
typedef __attribute__((ext_vector_type(4))) float f32x4;

// ws layout
#define OFF_H0   0u            // [4][512][512] f16
#define OFF_H1   2097152u      // [4][512][512] f16
#define OFF_W0T  4194304u      // [512][640]  f16 (W0T[c][k], k<128:Wih0, else Whh0)
#define OFF_W1T  4849664u      // [512][1024] f16 (W1T[c][k], k<512:Wih1, else Whh1)
#define OFF_WOT  5898240u      // [128][512]  f16 (WoutT[v][k])
#define OFF_EMB  6029312u      // [128][128]  f16
#define OFF_FLAG 6062080u      // [16 groups][16] int
#define OFF_CTR  6063104u      // [16] int per-XCD slot counters
#define WS_TOTAL 6063168u

// static LDS layout — row-major, +16B pad per row (strides are 16B multiples)
// stage0: lw0 [64] stride 1296 @0 | lwo [16] stride 1040 @82944 | lemb [128] stride 272 @99584
// stage1: lw1 [64] stride 2064 @0
#define L_WO   82944
#define L_EMB  99584
#define ST_W0  1296
#define ST_WO  1040
#define ST_EM  272
#define ST_W1  2064
#define LDS_BYTES 134400

__device__ __forceinline__ f16x8 ld8(const f16* p) {
    return *reinterpret_cast<const f16x8*>(p);
}
__device__ __forceinline__ f16x8 lds_frag(const char* lds, int rowByte, int kElem) {
    return *reinterpret_cast<const f16x8*>(lds + rowByte + kElem * 2);
}
// Agent-acquire vL1/L2 invalidate (R13-proven): drain vmem, then buffer_inv sc1.
#define INV_L1() asm volatile("s_waitcnt vmcnt(0)\n\tbuffer_inv sc1" ::: "memory")
#define MFMA16(a, b, c) __builtin_amdgcn_mfma_f32_16x16x32_f16((a), (b), (c), 0, 0, 0)

__global__ void prep_kernel(const float* __restrict__ Wih0, const float* __restrict__ Whh0,
                            const float* __restrict__ Wih1, const float* __restrict__ Whh1,
                            const float* __restrict__ Wout, const float* __restrict__ emb,
                            char* __restrict__ ws)
{
    f16* w0t = (f16*)(ws + OFF_W0T);
    f16* w1t = (f16*)(ws + OFF_W1T);
    f16* wot = (f16*)(ws + OFF_WOT);
    f16* e16 = (f16*)(ws + OFF_EMB);
    const int N0 = 512 * 640, N1 = 512 * 1024, N2 = 128 * 512, NE = 128 * 128;
    int i = blockIdx.x * blockDim.x + threadIdx.x;
    if (i < N0) {
        int c = i / 640, k = i - c * 640;
        w0t[i] = (f16)((k < 128) ? Wih0[k * 512 + c] : Whh0[(k - 128) * 512 + c]);
    } else if (i < N0 + N1) {
        int j = i - N0;
        int c = j >> 10, k = j & 1023;
        w1t[j] = (f16)((k < 512) ? Wih1[k * 512 + c] : Whh1[(k - 512) * 512 + c]);
    } else if (i < N0 + N1 + N2) {
        int j = i - (N0 + N1);
        int v = j >> 9, k = j & 511;
        wot[j] = (f16)(Wout[k * 128 + v]);
    } else if (i < N0 + N1 + N2 + NE) {
        int j = i - (N0 + N1 + N2);
        e16[j] = (f16)(emb[j]);
    }
}

__global__ __launch_bounds__(512)
void rnn_kernel(
    const int* __restrict__ x,
    const float* __restrict__ bih0, const float* __restrict__ bhh0,
    const float* __restrict__ bih1, const float* __restrict__ bhh1,
    const float* __restrict__ bout, float* __restrict__ out,
    f16* __restrict__ h0buf, f16* __restrict__ h1buf,
    const f16* __restrict__ w0t, const f16* __restrict__ w1t,
    const f16* __restrict__ wot, const f16* __restrict__ e16,
    int* __restrict__ flags, int* __restrict__ xcdctr)
{
    static __shared__ __attribute__((aligned(16))) char lds[LDS_BYTES];
    const int tid = threadIdx.x;

    // --- dynamic XCD-local group assignment (group's 16 blocks share one L2) ---
    __shared__ __attribute__((aligned(16))) int sslot[4];
    if (tid == 0) {
        unsigned int xcc;
        asm volatile("s_getreg_b32 %0, hwreg(20, 0, 4)" : "=s"(xcc));   // HW_REG_XCC_ID
        int s = atomicAdd(&xcdctr[xcc & 15], 1);
        sslot[0] = (int)(xcc & 15);
        sslot[1] = s;
    }
    __syncthreads();
    const int xcd = sslot[0], slot = sslot[1];
    const int grp = xcd * 2 + (slot >> 4);   // batch group 0..15 (32 rows each)
    const int sub = slot & 15;
    const int stg = sub >> 3;                // 0 = layer0 (+projection), 1 = layer1
    const int jc  = sub & 7;                 // column slice 0..7 (64 cols)
    if (grp >= 16) return;
    const int row0 = grp * 32;
    const int col0 = jc * 64;

    int* gflags = flags + grp * 16;          // [0..7]=stage0, [8..15]=stage1

    __shared__ __attribute__((aligned(16))) int tok[32];
    __shared__ __attribute__((aligned(16))) float bs[64];

    const int lane = tid & 63;
    const int wv = tid >> 6;                 // wave 0..7
    const int mt = wv >> 2, nt = wv & 3;     // 2 M-tiles x 4 N-tiles
    const int ar = lane & 15;
    const int kg8 = (lane >> 4) << 3;
    const int arow = row0 + mt * 16 + ar;
    const int cB   = nt * 16 + ar;           // local output col 0..63
    const int rloc = mt * 16 + ((lane >> 4) << 2);   // local row base for C-frags

    // ---- stage weights into LDS (row-major, padded), once ----
    if (stg == 0) {
        for (int i = tid; i < 5120; i += 512) {            // lw0: 64 rows x 80 chunks
            int c = i / 80, kc = i - c * 80;
            *(f16x8*)(lds + c * ST_W0 + kc * 16) = ld8(w0t + (col0 + c) * 640 + kc * 8);
        }
        for (int i = tid; i < 1024; i += 512) {            // lwo: 16 rows x 64 chunks
            int r = i >> 6, kc = i & 63;
            *(f16x8*)(lds + L_WO + r * ST_WO + kc * 16) = ld8(wot + (jc * 16 + r) * 512 + kc * 8);
        }
        for (int i = tid; i < 2048; i += 512) {            // lemb: 128 rows x 16 chunks
            int r = i >> 4, kc = i & 15;
            *(f16x8*)(lds + L_EMB + r * ST_EM + kc * 16) = ld8(e16 + r * 128 + kc * 8);
        }
    } else {
        for (int i = tid; i < 8192; i += 512) {            // lw1: 64 rows x 128 chunks
            int c = i >> 7, kc = i & 127;
            *(f16x8*)(lds + c * ST_W1 + kc * 16) = ld8(w1t + (col0 + c) * 1024 + kc * 8);
        }
    }
    if (tid < 64) {
        bs[tid] = (stg == 0) ? (bih0[col0 + tid] + bhh0[col0 + tid])
                             : (bih1[col0 + tid] + bhh1[col0 + tid]);
    }
    __syncthreads();
    const float cbias = bs[cB];

    if (stg == 0) {
        // ---- layer 0: h0(t) = tanh([emb(x_t) | h0(t-1)] @ W0 + b0) + projection of h1(t-4) ----
        const int w0Row = cB * ST_W0;
        const int vcol = jc * 16 + ar;
        const float pbias = bout[vcol];
        const int woRow = L_WO + ar * ST_WO;
        const int prow_base = row0 + mt * 16;

        for (int t = 0; t < Ss; ++t) {
            if (tid >= 64 && tid < 96) tok[tid - 64] = x[(row0 + tid - 64) * Ss + t];
            if (tid < 16) {
                const int tgt = (tid < 8) ? t : (t - 3);
                int it = 0;
                while (__hip_atomic_load(&gflags[tid], __ATOMIC_RELAXED, __HIP_MEMORY_SCOPE_AGENT) < tgt) {
                    if (++it > (1 << 18)) break;
                    __builtin_amdgcn_s_sleep(1);
                }
            }
            __syncthreads();
            INV_L1();
            const int myTok = tok[mt * 16 + ar];
            const int embRow = L_EMB + myTok * ST_EM;
            f16x8 hf[16];
            const f16* ha = h0buf + ((t + 3) & 3) * (Bb * Hh) + arow * Hh + kg8;
            #pragma unroll
            for (int kc = 0; kc < 16; ++kc) hf[kc] = ld8(ha + kc * 32);
            f32x4 a0 = {0.f,0.f,0.f,0.f}, a1 = a0, a2 = a0, a3 = a0;
            #pragma unroll
            for (int kc = 0; kc < 4; ++kc) {
                f16x8 af = lds_frag(lds, embRow, kc * 32 + kg8);
                f16x8 bw = lds_frag(lds, w0Row, kc * 32 + kg8);
                if ((kc & 3) == 0) a0 = MFMA16(af, bw, a0);
                else if ((kc & 3) == 1) a1 = MFMA16(af, bw, a1);
                else if ((kc & 3) == 2) a2 = MFMA16(af, bw, a2);
                else a3 = MFMA16(af, bw, a3);
            }
            #pragma unroll
            for (int kc = 0; kc < 16; ++kc) {
                f16x8 bw = lds_frag(lds, w0Row, 128 + kc * 32 + kg8);
                if ((kc & 3) == 0) a0 = MFMA16(hf[kc], bw, a0);
                else if ((kc & 3) == 1) a1 = MFMA16(hf[kc], bw, a1);
                else if ((kc & 3) == 2) a2 = MFMA16(hf[kc], bw, a2);
                else a3 = MFMA16(hf[kc], bw, a3);
            }
            f32x4 acc = (a0 + a1) + (a2 + a3);
            // plain write-through stores -> shared XCD L2 (R6-proven path)
            f16* ho = h0buf + (t & 3) * (Bb * Hh) + (row0 + rloc) * Hh + col0 + cB;
            #pragma unroll
            for (int i = 0; i < 4; ++i) ho[i * Hh] = (f16)(tanhf(acc[i] + cbias));
            // projection of h1(t-4) -> logits(t-4); rotates across wave pairs (wv&3 == t&3)
            if (t >= 4 && (wv & 3) == (t & 3)) {
                const int tp = t - 4;
                f16x8 pf[16];
                const f16* pa = h1buf + (tp & 3) * (Bb * Hh) + (prow_base + ar) * Hh + kg8;
                #pragma unroll
                for (int kc = 0; kc < 16; ++kc) pf[kc] = ld8(pa + kc * 32);
                f32x4 p0 = {0.f,0.f,0.f,0.f}, p1 = p0, p2 = p0, p3 = p0;
                #pragma unroll
                for (int kc = 0; kc < 16; kc += 4) {
                    p0 = MFMA16(pf[kc + 0], lds_frag(lds, woRow, (kc + 0) * 32 + kg8), p0);
                    p1 = MFMA16(pf[kc + 1], lds_frag(lds, woRow, (kc + 1) * 32 + kg8), p1);
                    p2 = MFMA16(pf[kc + 2], lds_frag(lds, woRow, (kc + 2) * 32 + kg8), p2);
                    p3 = MFMA16(pf[kc + 3], lds_frag(lds, woRow, (kc + 3) * 32 + kg8), p3);
                }
                f32x4 pr = (p0 + p1) + (p2 + p3);
                float* op = out + (size_t)(prow_base + ((lane >> 4) << 2)) * (Ss * Vv) + tp * Vv + vcol;
                #pragma unroll
                for (int i = 0; i < 4; ++i) op[i * (Ss * Vv)] = pr[i] + pbias;
            }
            __syncthreads();   // drains vmcnt: h0 stores (write-through) in L2 before flag
            if (tid == 0)
                __hip_atomic_store(&gflags[jc], t + 1, __ATOMIC_RELAXED, __HIP_MEMORY_SCOPE_AGENT);
        }
        // ---- tail: project h1(252..255); one step per wave (wv&3), both M-tiles ----
        if (tid < 8) {
            int it = 0;
            while (__hip_atomic_load(&gflags[8 + tid], __ATOMIC_RELAXED, __HIP_MEMORY_SCOPE_AGENT) < Ss) {
                if (++it > (1 << 18)) break;
                __builtin_amdgcn_s_sleep(1);
            }
        }
        __syncthreads();
        INV_L1();
        {
            const int tp = 252 + (wv & 3);
            f16x8 pf[16];
            const f16* pa = h1buf + (tp & 3) * (Bb * Hh) + (prow_base + ar) * Hh + kg8;
            #pragma unroll
            for (int kc = 0; kc < 16; ++kc) pf[kc] = ld8(pa + kc * 32);
            f32x4 p0 = {0.f,0.f,0.f,0.f}, p1 = p0, p2 = p0, p3 = p0;
            #pragma unroll
            for (int kc = 0; kc < 16; kc += 4) {
                p0 = MFMA16(pf[kc + 0], lds_frag(lds, woRow, (kc + 0) * 32 + kg8), p0);
                p1 = MFMA16(pf[kc + 1], lds_frag(lds, woRow, (kc + 1) * 32 + kg8), p1);
                p2 = MFMA16(pf[kc + 2], lds_frag(lds, woRow, (kc + 2) * 32 + kg8), p2);
                p3 = MFMA16(pf[kc + 3], lds_frag(lds, woRow, (kc + 3) * 32 + kg8), p3);
            }
            f32x4 pr = (p0 + p1) + (p2 + p3);
            float* op = out + (size_t)(prow_base + ((lane >> 4) << 2)) * (Ss * Vv) + tp * Vv + vcol;
            #pragma unroll
            for (int i = 0; i < 4; ++i) op[i * (Ss * Vv)] = pr[i] + pbias;
        }
    } else {
        // ---- layer 1: h1(t) = tanh([h0(t) | h1(t-1)] @ W1 + b1) ----
        const int w1Row = cB * ST_W1;
        for (int t = 0; t < Ss; ++t) {
            if (tid < 16) {
                const int tgt = (tid < 8) ? (t + 1) : t;
                int it = 0;
                while (__hip_atomic_load(&gflags[tid], __ATOMIC_RELAXED, __HIP_MEMORY_SCOPE_AGENT) < tgt) {
                    if (++it > (1 << 18)) break;
                    __builtin_amdgcn_s_sleep(1);
                }
            }
            __syncthreads();
            INV_L1();
            f16x8 hf[16], gf[16];
            const f16* h0a = h0buf + (t & 3) * (Bb * Hh) + arow * Hh + kg8;
            const f16* h1a = h1buf + ((t + 3) & 3) * (Bb * Hh) + arow * Hh + kg8;
            #pragma unroll
            for (int kc = 0; kc < 16; ++kc) hf[kc] = ld8(h0a + kc * 32);
            #pragma unroll
            for (int kc = 0; kc < 16; ++kc) gf[kc] = ld8(h1a + kc * 32);
            f32x4 a0 = {0.f,0.f,0.f,0.f}, a1 = a0, a2 = a0, a3 = a0;
            #pragma unroll
            for (int kc = 0; kc < 16; kc += 4) {
                a0 = MFMA16(hf[kc + 0], lds_frag(lds, w1Row, (kc + 0) * 32 + kg8), a0);
                a1 = MFMA16(hf[kc + 1], lds_frag(lds, w1Row, (kc + 1) * 32 + kg8), a1);
                a2 = MFMA16(hf[kc + 2], lds_frag(lds, w1Row, (kc + 2) * 32 + kg8), a2);
                a3 = MFMA16(hf[kc + 3], lds_frag(lds, w1Row, (kc + 3) * 32 + kg8), a3);
            }
            #pragma unroll
            for (int kc = 0; kc < 16; kc += 4) {
                a0 = MFMA16(gf[kc + 0], lds_frag(lds, w1Row, 512 + (kc + 0) * 32 + kg8), a0);
                a1 = MFMA16(gf[kc + 1], lds_frag(lds, w1Row, 512 + (kc + 1) * 32 + kg8), a1);
                a2 = MFMA16(gf[kc + 2], lds_frag(lds, w1Row, 512 + (kc + 2) * 32 + kg8), a2);
                a3 = MFMA16(gf[kc + 3], lds_frag(lds, w1Row, 512 + (kc + 3) * 32 + kg8), a3);
            }
            f32x4 acc = (a0 + a1) + (a2 + a3);
            f16* ho = h1buf + (t & 3) * (Bb * Hh) + (row0 + rloc) * Hh + col0 + cB;
            #pragma unroll
            for (int i = 0; i < 4; ++i) ho[i * Hh] = (f16)(tanhf(acc[i] + cbias));
            __syncthreads();   // drains vmcnt: h1 stores in L2 before flag
            if (tid == 0)
                __hip_atomic_store(&gflags[8 + jc], t + 1, __ATOMIC_RELAXED, __HIP_MEMORY_SCOPE_AGENT);
        }
    }
}

extern "C" void kernel_launch(void* const* d_in, const int* in_sizes, int n_in,
                              void* d_out, int out_size, void* d_ws, size_t ws_size,
                              hipStream_t stream) {
    const int*   x    = (const int*)d_in[0];
    const float* emb  = (const float*)d_in[1];
    const float* Wih0 = (const float*)d_in[2];
    const float* bih0 = (const float*)d_in[3];
    const float* Whh0 = (const float*)d_in[4];
    const float* bhh0 = (const float*)d_in[5];
    const float* Wih1 = (const float*)d_in[6];
    const float* bih1 = (const float*)d_in[7];
    const float* Whh1 = (const float*)d_in[8];
    const float* bhh1 = (const float*)d_in[9];
    const float* Wout = (const float*)d_in[10];
    const float* bout = (const float*)d_in[11];
    float* out = (float*)d_out;
    char*  ws  = (char*)d_ws;

    hipMemsetAsync(d_ws, 0, WS_TOTAL, stream);

    {
        const int total = 512 * 640 + 512 * 1024 + 128 * 512 + 128 * 128;
        prep_kernel<<<(total + 1023) / 1024, 1024, 0, stream>>>(Wih0, Whh0, Wih1, Whh1, Wout, emb, ws);
    }

    f16* h0buf = (f16*)(ws + OFF_H0);
    f16* h1buf = (f16*)(ws + OFF_H1);
    f16* w0t   = (f16*)(ws + OFF_W0T);
    f16* w1t   = (f16*)(ws + OFF_W1T);
    f16* wot   = (f16*)(ws + OFF_WOT);
    f16* e16   = (f16*)(ws + OFF_EMB);
    int* flags = (int*)(ws + OFF_FLAG);
    int* ctr   = (int*)(ws + OFF_CTR);

    void* args[] = { (void*)&x, (void*)&bih0, (void*)&bhh0, (void*)&bih1, (void*)&bhh1,
                     (void*)&bout, (void*)&out, (void*)&h0buf, (void*)&h1buf,
                     (void*)&w0t, (void*)&w1t, (void*)&wot, (void*)&e16,
                     (void*)&flags, (void*)&ctr };
    hipLaunchCooperativeKernel((void*)rnn_kernel, dim3(256), dim3(512), args, 0, stream);
}